// Round 10
// baseline (293.577 us; speedup 1.0000x reference)
//
#include <hip/hip_runtime.h>

#define NN 50000
#define NPAD 50064             // padded rows for MFMA tail reads
#define EE 800000
#define DD 64
#define BN_EPS 1e-5f

#define NPART 8
#define PART_NODES 6250        // 50000/8
#define CAP 64                 // padded CSR slots per node
#define BCAP 131072            // bucket capacity per partition
#define NSCAT 32               // scatter blocks per partition
#define NB_BUCKET 782          // ceil(800000/1024)
#define NB_AGG  12500          // 4 nodes (waves) per block
#define NB_MLP  782            // 64 rows per block (4 waves x 16)
#define NB_SETUP 1563          // covers 400000 cvt threads
#define NB_ELT8 1563
#define NB_APPLY 3125

typedef __attribute__((ext_vector_type(8))) short short8v;   // 8 bf16 = 4 VGPR
typedef __attribute__((ext_vector_type(4))) float float4v;   // MFMA acc

__device__ __forceinline__ unsigned bfpack2(float a, float b) {
    union { float f; unsigned u; } ua, ub;
    ua.f = a; ub.f = b;
    unsigned ra = ua.u + 0x7fffu + ((ua.u >> 16) & 1u);
    unsigned rb = ub.u + 0x7fffu + ((ub.u >> 16) & 1u);
    return (ra >> 16) | (rb & 0xffff0000u);
}

__device__ __forceinline__ unsigned short bf16of(float v) {
    union { float f; unsigned u; } x; x.f = v;
    unsigned r = x.u + 0x7fffu + ((x.u >> 16) & 1u);
    return (unsigned short)(r >> 16);
}

// setup: x -> bf16 halves, W -> bf16 transposed, zero bucketCnt + stats
__global__ __launch_bounds__(256) void k_setup(const float* __restrict__ x,
                                               unsigned* __restrict__ xb0,
                                               unsigned* __restrict__ xb1,
                                               const float* __restrict__ W1,
                                               const float* __restrict__ W2,
                                               unsigned short* __restrict__ Wb,
                                               int* __restrict__ bucketCnt,
                                               float* __restrict__ stats) {
    int t = blockIdx.x * 256 + threadIdx.x;
    if (t < NN * 8) {
        int row = t >> 3, c8 = t & 7;
        const float4* p = (const float4*)(x + (size_t)row * 64 + c8 * 8);
        float4 a = p[0], b = p[1];
        uint4 o;
        o.x = bfpack2(a.x, a.y); o.y = bfpack2(a.z, a.w);
        o.z = bfpack2(b.x, b.y); o.w = bfpack2(b.z, b.w);
        unsigned* dp = (c8 < 4) ? xb0 : xb1;
        ((uint4*)dp)[(size_t)row * 4 + (c8 & 3)] = o;
    }
    if (t < 3 * 2 * 4096) {
        int l = t / 8192;
        int rem = t - l * 8192;
        int m = rem / 4096;
        int e = rem - m * 4096;
        int c = e >> 6, k = e & 63;
        const float* W = (m == 0 ? W1 : W2) + l * 4096;
        Wb[t] = bf16of(W[k * 64 + c]);
    }
    if (t < 128) bucketCnt[t] = 0;
    else if (t < 512) stats[t - 128] = 0.f;
}

// phase A: bucket edges by dst partition (one pass over edges) + zero cursor
__global__ __launch_bounds__(1024) void k_build(const int* __restrict__ src,
                                                const int* __restrict__ dst,
                                                unsigned long long* __restrict__ bucket,
                                                int* __restrict__ bucketCnt,
                                                int* __restrict__ cursor) {
    __shared__ int lcnt[8];
    __shared__ int lbase[8];
    int t = threadIdx.x;
    int g = blockIdx.x * 1024 + t;
    if (g < NN) cursor[g] = 0;
    if (t < 8) lcnt[t] = 0;
    __syncthreads();
    int d = 0, s = 0, p = 0, loc = 0;
    bool ok = (g < EE);
    if (ok) {
        d = __builtin_nontemporal_load(dst + g);
        s = __builtin_nontemporal_load(src + g);
        p = (unsigned)d / PART_NODES;
        loc = atomicAdd(&lcnt[p], 1);
    }
    __syncthreads();
    if (t < 8) lbase[t] = atomicAdd(&bucketCnt[t * 16], lcnt[t]);
    __syncthreads();
    if (ok) {
        unsigned long long v = ((unsigned long long)(unsigned)s << 32) | (unsigned)d;
        bucket[(size_t)p * BCAP + lbase[p] + loc] = v;
    }
}

// phase B: scatter bucket p into col slice p (dirty lines stay on one XCD)
__global__ __launch_bounds__(256) void k_scatter(const unsigned long long* __restrict__ bucket,
                                                 const int* __restrict__ bucketCnt,
                                                 int* __restrict__ cursor,
                                                 int* __restrict__ col) {
    int p = blockIdx.x & 7;
    int cnt = bucketCnt[p * 16];
    const unsigned long long* b = bucket + (size_t)p * BCAP;
    for (int i = (blockIdx.x >> 3) * 256 + threadIdx.x; i < cnt; i += NSCAT * 256) {
        unsigned long long v = __builtin_nontemporal_load(b + i);
        int d = (int)(v & 0xffffffffu);
        int s = (int)(v >> 32);
        int pos = atomicAdd(&cursor[d], 1);
        col[d * CAP + pos] = s;
    }
}

// half-feature gather: z[i, half] = h[i,half] + sum_j h[j,half].
// Rows are 32 bf16 = 64 B = one cache line; per-XCD gather set 3.2 MB < 4 MB L2.
// lane = slot*4 + li: 16 neighbor slots x 4 chunks of 16 B.
__global__ __launch_bounds__(256) void k_agg5(const unsigned* __restrict__ hbH,
                                              const int* __restrict__ deg,
                                              const int* __restrict__ col,
                                              unsigned* __restrict__ outH) {
    int node = blockIdx.x * 4 + (threadIdx.x >> 6);   // grid exact: 12500*4
    int lane = threadIdx.x & 63;
    int li = lane & 3;
    int slot = lane >> 2;
    int dn = deg[node];
    int base = node * CAP;
    const uint4* hb4 = (const uint4*)hbH;
    float acc[8];
#pragma unroll
    for (int i = 0; i < 8; ++i) acc[i] = 0.f;

#define UNPK_ADD(U)                                                      \
    {                                                                    \
        uint4 _u = (U);                                                  \
        union { unsigned u; float f; } l0, h0, l1, h1, l2, h2, l3, h3;   \
        l0.u = _u.x << 16; h0.u = _u.x & 0xffff0000u;                    \
        l1.u = _u.y << 16; h1.u = _u.y & 0xffff0000u;                    \
        l2.u = _u.z << 16; h2.u = _u.z & 0xffff0000u;                    \
        l3.u = _u.w << 16; h3.u = _u.w & 0xffff0000u;                    \
        acc[0] += l0.f; acc[1] += h0.f; acc[2] += l1.f; acc[3] += h1.f;  \
        acc[4] += l2.f; acc[5] += h2.f; acc[6] += l3.f; acc[7] += h3.f;  \
    }

    if (slot == 0)
        UNPK_ADD(hb4[(size_t)node * 4 + li]);   // self row

    for (int k = slot; k < dn; k += 16) {
        int s = __builtin_nontemporal_load(col + base + k);
        UNPK_ADD(hb4[(size_t)s * 4 + li]);
    }
#undef UNPK_ADD

#pragma unroll
    for (int i = 0; i < 8; ++i) acc[i] += __shfl_xor(acc[i], 4);
#pragma unroll
    for (int i = 0; i < 8; ++i) acc[i] += __shfl_xor(acc[i], 8);
#pragma unroll
    for (int i = 0; i < 8; ++i) acc[i] += __shfl_xor(acc[i], 16);
#pragma unroll
    for (int i = 0; i < 8; ++i) acc[i] += __shfl_xor(acc[i], 32);

    if (slot == 0) {
        unsigned p0 = bfpack2(acc[0], acc[1]);
        unsigned p1 = bfpack2(acc[2], acc[3]);
        unsigned p2 = bfpack2(acc[4], acc[5]);
        unsigned p3 = bfpack2(acc[6], acc[7]);
        // NT store: don't let the output stream evict the gather set
        unsigned long long* q =
            (unsigned long long*)(outH + ((size_t)node * 4 + li) * 4);
        __builtin_nontemporal_store(((unsigned long long)p1 << 32) | p0, q);
        __builtin_nontemporal_store(((unsigned long long)p3 << 32) | p2, q + 1);
    }
}

// MFMA MLP + fused BN stats: Zf = relu(Zb@W1+b1)@W2+b2; statsL += colsum/sumsq.
// Wave = 16 rows x 64 cols. A-frag: lane l = row (l&15), k = (l>>4)*8..+7.
// C: col = lane&15, row = (lane>>4)*4 + r  [m89 verified; validated round 9].
__global__ __launch_bounds__(256) void k_mlp_mfma(const unsigned short* __restrict__ Zb0,
                                                  const unsigned short* __restrict__ Zb1,
                                                  const unsigned short* __restrict__ WbL,
                                                  const float* __restrict__ b1,
                                                  const float* __restrict__ b2,
                                                  float* __restrict__ Zf,
                                                  float* __restrict__ statsL) {
    __shared__ unsigned short sm[4][16 * 72];   // padded stride 72 u16
    __shared__ float sred[2][4][64];
    int w = threadIdx.x >> 6;
    int lane = threadIdx.x & 63;
    int q = lane >> 4;
    int cl = lane & 15;
    int r0 = blockIdx.x * 64 + w * 16;

    short8v B1[4][2], B2[4][2];
#pragma unroll
    for (int t = 0; t < 4; ++t) {
#pragma unroll
        for (int h = 0; h < 2; ++h) {
            B1[t][h] = *(const short8v*)(WbL + ((t * 16 + cl) * 64 + h * 32 + q * 8));
            B2[t][h] = *(const short8v*)(WbL + 4096 + ((t * 16 + cl) * 64 + h * 32 + q * 8));
        }
    }

    int arow = r0 + cl;
    short8v a0 = *(const short8v*)(Zb0 + (size_t)arow * 32 + q * 8);
    short8v a1 = *(const short8v*)(Zb1 + (size_t)arow * 32 + q * 8);

    float4v acc1[4];
#pragma unroll
    for (int t = 0; t < 4; ++t) {
        float b = b1[t * 16 + cl];
        acc1[t] = (float4v){b, b, b, b};
        acc1[t] = __builtin_amdgcn_mfma_f32_16x16x32_bf16(a0, B1[t][0], acc1[t], 0, 0, 0);
        acc1[t] = __builtin_amdgcn_mfma_f32_16x16x32_bf16(a1, B1[t][1], acc1[t], 0, 0, 0);
    }

    unsigned short* s = sm[w];
#pragma unroll
    for (int t = 0; t < 4; ++t) {
#pragma unroll
        for (int r = 0; r < 4; ++r) {
            float v = fmaxf(acc1[t][r], 0.f);
            s[(q * 4 + r) * 72 + t * 16 + cl] = bf16of(v);
        }
    }

    short8v a2_0 = *(const short8v*)(s + cl * 72 + q * 8);
    short8v a2_1 = *(const short8v*)(s + cl * 72 + 32 + q * 8);

    float4v acc2[4];
#pragma unroll
    for (int t = 0; t < 4; ++t) {
        float b = b2[t * 16 + cl];
        acc2[t] = (float4v){b, b, b, b};
        acc2[t] = __builtin_amdgcn_mfma_f32_16x16x32_bf16(a2_0, B2[t][0], acc2[t], 0, 0, 0);
        acc2[t] = __builtin_amdgcn_mfma_f32_16x16x32_bf16(a2_1, B2[t][1], acc2[t], 0, 0, 0);
    }

#pragma unroll
    for (int t = 0; t < 4; ++t) {
#pragma unroll
        for (int r = 0; r < 4; ++r) {
            int row = r0 + q * 4 + r;
            if (row < NN) Zf[(size_t)row * 64 + t * 16 + cl] = acc2[t][r];
        }
    }

    // fused per-column stats over this wave's 16 rows (pad rows masked)
#pragma unroll
    for (int t = 0; t < 4; ++t) {
        float sv = 0.f, qv = 0.f;
#pragma unroll
        for (int r = 0; r < 4; ++r) {
            int row = r0 + q * 4 + r;
            float v = (row < NN) ? acc2[t][r] : 0.f;
            sv += v;
            qv = fmaf(v, v, qv);
        }
        sv += __shfl_xor(sv, 16); sv += __shfl_xor(sv, 32);
        qv += __shfl_xor(qv, 16); qv += __shfl_xor(qv, 32);
        if (lane < 16) {
            sred[0][w][t * 16 + cl] = sv;
            sred[1][w][t * 16 + cl] = qv;
        }
    }
    __syncthreads();
    int tt = threadIdx.x;
    if (tt < 128) {
        int which = tt >> 6, c = tt & 63;
        float tot = sred[which][0][c] + sred[which][1][c] +
                    sred[which][2][c] + sred[which][3][c];
        atomicAdd(&statsL[which * 64 + c], tot);
    }
}

// BN affine (inline from statsL) + ReLU + bf16 pack into halves
__global__ __launch_bounds__(256) void k_bnapply16(const float* __restrict__ Z,
                                                   const float* __restrict__ statsL,
                                                   const float* __restrict__ gammaL,
                                                   const float* __restrict__ betaL,
                                                   unsigned* __restrict__ hb0,
                                                   unsigned* __restrict__ hb1) {
    __shared__ float sa[64];
    __shared__ float sc[64];
    int tt = threadIdx.x;
    if (tt < 64) {
        float mean = statsL[tt] * (1.f / NN);
        float var = statsL[64 + tt] * (1.f / NN) - mean * mean;
        float a = gammaL[tt] * rsqrtf(var + BN_EPS);
        sa[tt] = a;
        sc[tt] = fmaf(-mean, a, betaL[tt]);
    }
    __syncthreads();
    int t = blockIdx.x * 256 + tt;
    if (t >= NN * 8) return;
    int row = t >> 3, c8 = t & 7;
    int cb = c8 * 8;
    const float4* p = (const float4*)(Z + (size_t)row * 64 + cb);
    float4 a = p[0], b = p[1];
    a.x = fmaxf(fmaf(a.x, sa[cb + 0], sc[cb + 0]), 0.f);
    a.y = fmaxf(fmaf(a.y, sa[cb + 1], sc[cb + 1]), 0.f);
    a.z = fmaxf(fmaf(a.z, sa[cb + 2], sc[cb + 2]), 0.f);
    a.w = fmaxf(fmaf(a.w, sa[cb + 3], sc[cb + 3]), 0.f);
    b.x = fmaxf(fmaf(b.x, sa[cb + 4], sc[cb + 4]), 0.f);
    b.y = fmaxf(fmaf(b.y, sa[cb + 5], sc[cb + 5]), 0.f);
    b.z = fmaxf(fmaf(b.z, sa[cb + 6], sc[cb + 6]), 0.f);
    b.w = fmaxf(fmaf(b.w, sa[cb + 7], sc[cb + 7]), 0.f);
    uint4 o;
    o.x = bfpack2(a.x, a.y); o.y = bfpack2(a.z, a.w);
    o.z = bfpack2(b.x, b.y); o.w = bfpack2(b.z, b.w);
    unsigned* dp = (c8 < 4) ? hb0 : hb1;
    ((uint4*)dp)[(size_t)row * 4 + (c8 & 3)] = o;
}

// final BN apply (affine inline, no relu, f32 out)
__global__ __launch_bounds__(256) void k_apply_aff(const float* __restrict__ B,
                                                   const float* __restrict__ statsL,
                                                   const float* __restrict__ gammaL,
                                                   const float* __restrict__ betaL,
                                                   float* __restrict__ out) {
    __shared__ float sa[64];
    __shared__ float sc[64];
    int t = threadIdx.x;
    if (t < 64) {
        float mean = statsL[t] * (1.f / NN);
        float var = statsL[64 + t] * (1.f / NN) - mean * mean;
        float a = gammaL[t] * rsqrtf(var + BN_EPS);
        sa[t] = a;
        sc[t] = fmaf(-mean, a, betaL[t]);
    }
    __syncthreads();
    int i4 = blockIdx.x * 256 + t;
    if (i4 >= NN * 16) return;
    int cb = (i4 & 15) * 4;
    float4 v = ((const float4*)B)[i4];
    float4 o;
    o.x = fmaf(v.x, sa[cb + 0], sc[cb + 0]);
    o.y = fmaf(v.y, sa[cb + 1], sc[cb + 1]);
    o.z = fmaf(v.z, sa[cb + 2], sc[cb + 2]);
    o.w = fmaf(v.w, sa[cb + 3], sc[cb + 3]);
    ((float4*)out)[i4] = o;
}

extern "C" void kernel_launch(void* const* d_in, const int* in_sizes, int n_in,
                              void* d_out, int out_size, void* d_ws, size_t ws_size,
                              hipStream_t stream) {
    const float* x     = (const float*)d_in[0];
    const int*   ei    = (const int*)d_in[1];   // [2][E]
    const float* W1    = (const float*)d_in[2];
    const float* b1    = (const float*)d_in[3];
    const float* W2    = (const float*)d_in[4];
    const float* b2    = (const float*)d_in[5];
    const float* gamma = (const float*)d_in[6];
    const float* beta  = (const float*)d_in[7];
    float* out = (float*)d_out;

    const int* src = ei;        // edge_index[0]
    const int* dst = ei + EE;   // edge_index[1]

    char* w = (char*)d_ws;
    unsigned* Zb0 = (unsigned*)w; w += (size_t)NPAD * 32 * 2;   // bf16 half (3.2 MB)
    unsigned* Zb1 = (unsigned*)w; w += (size_t)NPAD * 32 * 2;
    unsigned* Hb0 = (unsigned*)w; w += (size_t)NPAD * 32 * 2;
    unsigned* Hb1 = (unsigned*)w; w += (size_t)NPAD * 32 * 2;
    unsigned* Xb0 = (unsigned*)w; w += (size_t)NPAD * 32 * 2;
    unsigned* Xb1 = (unsigned*)w; w += (size_t)NPAD * 32 * 2;
    float*    Zf  = (float*)w;    w += (size_t)NN * DD * 4;     // 12.8 MB
    int*      col = (int*)w;      w += (size_t)NN * CAP * 4;    // 12.8 MB
    unsigned long long* bucket = (unsigned long long*)w;
    w += (size_t)NPART * BCAP * 8;                              // 8.4 MB
    int*      cursor    = (int*)w; w += (size_t)NN * 4;
    int*      bucketCnt = (int*)w; w += 128 * 4;
    float*    stats     = (float*)w; w += 384 * 4;              // 3 layers x 128
    unsigned short* Wb  = (unsigned short*)w; w += 3 * 2 * 4096 * 2;

    // ---- setup + CSR build ----
    k_setup<<<NB_SETUP, 256, 0, stream>>>(x, Xb0, Xb1, W1, W2, Wb, bucketCnt, stats);
    k_build<<<NB_BUCKET, 1024, 0, stream>>>(src, dst, bucket, bucketCnt, cursor);
    k_scatter<<<NPART * NSCAT, 256, 0, stream>>>(bucket, bucketCnt, cursor, col);

    // ---- layer 0 ----
    k_agg5<<<NB_AGG, 256, 0, stream>>>(Xb0, cursor, col, Zb0);
    k_agg5<<<NB_AGG, 256, 0, stream>>>(Xb1, cursor, col, Zb1);
    k_mlp_mfma<<<NB_MLP, 256, 0, stream>>>((unsigned short*)Zb0, (unsigned short*)Zb1,
                                           Wb, b1, b2, Zf, stats);
    k_bnapply16<<<NB_ELT8, 256, 0, stream>>>(Zf, stats, gamma, beta, Hb0, Hb1);

    // ---- layer 1 ----
    k_agg5<<<NB_AGG, 256, 0, stream>>>(Hb0, cursor, col, Zb0);
    k_agg5<<<NB_AGG, 256, 0, stream>>>(Hb1, cursor, col, Zb1);
    k_mlp_mfma<<<NB_MLP, 256, 0, stream>>>((unsigned short*)Zb0, (unsigned short*)Zb1,
                                           Wb + 8192, b1 + 64, b2 + 64, Zf, stats + 128);
    k_bnapply16<<<NB_ELT8, 256, 0, stream>>>(Zf, stats + 128, gamma + 64, beta + 64, Hb0, Hb1);

    // ---- layer 2 ----
    k_agg5<<<NB_AGG, 256, 0, stream>>>(Hb0, cursor, col, Zb0);
    k_agg5<<<NB_AGG, 256, 0, stream>>>(Hb1, cursor, col, Zb1);
    k_mlp_mfma<<<NB_MLP, 256, 0, stream>>>((unsigned short*)Zb0, (unsigned short*)Zb1,
                                           Wb + 16384, b1 + 128, b2 + 128, Zf, stats + 256);
    k_apply_aff<<<NB_APPLY, 256, 0, stream>>>(Zf, stats + 256, gamma + 128, beta + 128, out);
}

// Round 12
// 239.529 us; speedup vs baseline: 1.2256x; 1.2256x over previous
//
#include <hip/hip_runtime.h>

#define NN 50000
#define NPAD 50064             // padded rows for MFMA tail reads
#define EE 800000
#define DD 64
#define BN_EPS 1e-5f

#define NPART 8
#define PART_NODES 6250        // 50000/8
#define CAP 64                 // padded CSR slots per node
#define BCAP 131072            // bucket capacity per partition
#define NSCAT 32               // scatter blocks per partition
#define NB_BUCKET 782          // ceil(800000/1024)
#define NB_AGG  12500          // 4 nodes (waves) per block
#define NB_MLP  782            // 64 rows per block (4 waves x 16)
#define NB_SETUP 1563          // covers 400000 cvt threads
#define NB_ELT8 1563
#define NB_APPLY 3125

typedef __attribute__((ext_vector_type(8))) short short8v;   // 8 bf16 = 4 VGPR
typedef __attribute__((ext_vector_type(4))) float float4v;   // MFMA acc

__device__ __forceinline__ unsigned bfpack2(float a, float b) {
    union { float f; unsigned u; } ua, ub;
    ua.f = a; ub.f = b;
    unsigned ra = ua.u + 0x7fffu + ((ua.u >> 16) & 1u);
    unsigned rb = ub.u + 0x7fffu + ((ub.u >> 16) & 1u);
    return (ra >> 16) | (rb & 0xffff0000u);
}

__device__ __forceinline__ unsigned short bf16of(float v) {
    union { float f; unsigned u; } x; x.f = v;
    unsigned r = x.u + 0x7fffu + ((x.u >> 16) & 1u);
    return (unsigned short)(r >> 16);
}

// setup: x -> bf16 (full width), W -> bf16 transposed, zero bucketCnt + stats
__global__ __launch_bounds__(256) void k_setup(const float* __restrict__ x,
                                               unsigned* __restrict__ xb,
                                               const float* __restrict__ W1,
                                               const float* __restrict__ W2,
                                               unsigned short* __restrict__ Wb,
                                               int* __restrict__ bucketCnt,
                                               float* __restrict__ stats) {
    int t = blockIdx.x * 256 + threadIdx.x;
    if (t < NN * 8) {
        const float4* p = (const float4*)(x + (size_t)t * 8);
        float4 a = p[0], b = p[1];
        uint4 o;
        o.x = bfpack2(a.x, a.y); o.y = bfpack2(a.z, a.w);
        o.z = bfpack2(b.x, b.y); o.w = bfpack2(b.z, b.w);
        ((uint4*)xb)[t] = o;
    }
    if (t < 3 * 2 * 4096) {
        int l = t / 8192;
        int rem = t - l * 8192;
        int m = rem / 4096;
        int e = rem - m * 4096;
        int c = e >> 6, k = e & 63;
        const float* W = (m == 0 ? W1 : W2) + l * 4096;
        Wb[t] = bf16of(W[k * 64 + c]);
    }
    if (t < 128) bucketCnt[t] = 0;
    else if (t < 512) stats[t - 128] = 0.f;
}

// phase A: bucket edges by dst partition (one pass over edges) + zero cursor
__global__ __launch_bounds__(1024) void k_build(const int* __restrict__ src,
                                                const int* __restrict__ dst,
                                                unsigned long long* __restrict__ bucket,
                                                int* __restrict__ bucketCnt,
                                                int* __restrict__ cursor) {
    __shared__ int lcnt[8];
    __shared__ int lbase[8];
    int t = threadIdx.x;
    int g = blockIdx.x * 1024 + t;
    if (g < NN) cursor[g] = 0;
    if (t < 8) lcnt[t] = 0;
    __syncthreads();
    int d = 0, s = 0, p = 0, loc = 0;
    bool ok = (g < EE);
    if (ok) {
        d = __builtin_nontemporal_load(dst + g);
        s = __builtin_nontemporal_load(src + g);
        p = (unsigned)d / PART_NODES;
        loc = atomicAdd(&lcnt[p], 1);
    }
    __syncthreads();
    if (t < 8) lbase[t] = atomicAdd(&bucketCnt[t * 16], lcnt[t]);
    __syncthreads();
    if (ok) {
        unsigned long long v = ((unsigned long long)(unsigned)s << 32) | (unsigned)d;
        bucket[(size_t)p * BCAP + lbase[p] + loc] = v;
    }
}

// phase B: scatter bucket p into col slice p (dirty lines stay on one XCD)
__global__ __launch_bounds__(256) void k_scatter(const unsigned long long* __restrict__ bucket,
                                                 const int* __restrict__ bucketCnt,
                                                 int* __restrict__ cursor,
                                                 int* __restrict__ col) {
    int p = blockIdx.x & 7;
    int cnt = bucketCnt[p * 16];
    const unsigned long long* b = bucket + (size_t)p * BCAP;
    for (int i = (blockIdx.x >> 3) * 256 + threadIdx.x; i < cnt; i += NSCAT * 256) {
        unsigned long long v = __builtin_nontemporal_load(b + i);
        int d = (int)(v & 0xffffffffu);
        int s = (int)(v >> 32);
        int pos = atomicAdd(&cursor[d], 1);
        col[d * CAP + pos] = s;
    }
}

// z[i,:] = h[i,:] + sum_j h[j,:] from bf16 rows (128 B); bf16 out (MLP input).
// Wave per node: lane = slot*8 + li; 8 slots x unroll-2 = 16 rows in flight.
__global__ __launch_bounds__(256) void k_agg4(const unsigned* __restrict__ hb,
                                              const int* __restrict__ deg,
                                              const int* __restrict__ col,
                                              unsigned* __restrict__ outZb) {
    int node = blockIdx.x * 4 + (threadIdx.x >> 6);   // grid exact: 12500*4
    int lane = threadIdx.x & 63;
    int li = lane & 7;
    int slot = lane >> 3;
    int dn = deg[node];
    int base = node * CAP;
    const uint4* hb4 = (const uint4*)hb;
    float acc[8];
#pragma unroll
    for (int i = 0; i < 8; ++i) acc[i] = 0.f;

#define UNPK_ADD(U)                                                      \
    {                                                                    \
        uint4 _u = (U);                                                  \
        union { unsigned u; float f; } l0, h0, l1, h1, l2, h2, l3, h3;   \
        l0.u = _u.x << 16; h0.u = _u.x & 0xffff0000u;                    \
        l1.u = _u.y << 16; h1.u = _u.y & 0xffff0000u;                    \
        l2.u = _u.z << 16; h2.u = _u.z & 0xffff0000u;                    \
        l3.u = _u.w << 16; h3.u = _u.w & 0xffff0000u;                    \
        acc[0] += l0.f; acc[1] += h0.f; acc[2] += l1.f; acc[3] += h1.f;  \
        acc[4] += l2.f; acc[5] += h2.f; acc[6] += l3.f; acc[7] += h3.f;  \
    }

    if (slot == 0)
        UNPK_ADD(hb4[(size_t)node * 8 + li]);   // self row

    int k = slot;
    for (; k + 8 < dn; k += 16) {
        int s0 = __builtin_nontemporal_load(col + base + k);
        int s1 = __builtin_nontemporal_load(col + base + k + 8);
        uint4 u0 = hb4[(size_t)s0 * 8 + li];
        uint4 u1 = hb4[(size_t)s1 * 8 + li];
        UNPK_ADD(u0);
        UNPK_ADD(u1);
    }
    if (k < dn) {
        int s0 = __builtin_nontemporal_load(col + base + k);
        UNPK_ADD(hb4[(size_t)s0 * 8 + li]);
    }
#undef UNPK_ADD

#pragma unroll
    for (int i = 0; i < 8; ++i) acc[i] += __shfl_xor(acc[i], 8);
#pragma unroll
    for (int i = 0; i < 8; ++i) acc[i] += __shfl_xor(acc[i], 16);
#pragma unroll
    for (int i = 0; i < 8; ++i) acc[i] += __shfl_xor(acc[i], 32);

    if (slot == 0) {
        uint4 o;
        o.x = bfpack2(acc[0], acc[1]);
        o.y = bfpack2(acc[2], acc[3]);
        o.z = bfpack2(acc[4], acc[5]);
        o.w = bfpack2(acc[6], acc[7]);
        ((uint4*)outZb)[(size_t)node * 8 + li] = o;
    }
}

// MFMA MLP + fused BN stats: Zf = relu(Zb@W1+b1)@W2+b2; statsL += colsum/sumsq.
// Wave = 16 rows x 64 cols. A-frag: lane l = row (l&15), k = (l>>4)*8..+7.
// C: col = lane&15, row = (lane>>4)*4 + r  [validated rounds 9/10].
__global__ __launch_bounds__(256) void k_mlp_mfma(const unsigned short* __restrict__ Zb,
                                                  const unsigned short* __restrict__ WbL,
                                                  const float* __restrict__ b1,
                                                  const float* __restrict__ b2,
                                                  float* __restrict__ Zf,
                                                  float* __restrict__ statsL) {
    __shared__ unsigned short sm[4][16 * 72];   // padded stride 72 u16
    __shared__ float sred[2][4][64];
    int w = threadIdx.x >> 6;
    int lane = threadIdx.x & 63;
    int q = lane >> 4;
    int cl = lane & 15;
    int r0 = blockIdx.x * 64 + w * 16;

    short8v B1[4][2], B2[4][2];
#pragma unroll
    for (int t = 0; t < 4; ++t) {
#pragma unroll
        for (int h = 0; h < 2; ++h) {
            B1[t][h] = *(const short8v*)(WbL + ((t * 16 + cl) * 64 + h * 32 + q * 8));
            B2[t][h] = *(const short8v*)(WbL + 4096 + ((t * 16 + cl) * 64 + h * 32 + q * 8));
        }
    }

    const unsigned short* zr = Zb + (size_t)(r0 + cl) * 64;
    short8v a0 = *(const short8v*)(zr + q * 8);
    short8v a1 = *(const short8v*)(zr + 32 + q * 8);

    float4v acc1[4];
#pragma unroll
    for (int t = 0; t < 4; ++t) {
        float b = b1[t * 16 + cl];
        acc1[t] = (float4v){b, b, b, b};
        acc1[t] = __builtin_amdgcn_mfma_f32_16x16x32_bf16(a0, B1[t][0], acc1[t], 0, 0, 0);
        acc1[t] = __builtin_amdgcn_mfma_f32_16x16x32_bf16(a1, B1[t][1], acc1[t], 0, 0, 0);
    }

    unsigned short* s = sm[w];
#pragma unroll
    for (int t = 0; t < 4; ++t) {
#pragma unroll
        for (int r = 0; r < 4; ++r) {
            float v = fmaxf(acc1[t][r], 0.f);
            s[(q * 4 + r) * 72 + t * 16 + cl] = bf16of(v);
        }
    }

    short8v a2_0 = *(const short8v*)(s + cl * 72 + q * 8);
    short8v a2_1 = *(const short8v*)(s + cl * 72 + 32 + q * 8);

    float4v acc2[4];
#pragma unroll
    for (int t = 0; t < 4; ++t) {
        float b = b2[t * 16 + cl];
        acc2[t] = (float4v){b, b, b, b};
        acc2[t] = __builtin_amdgcn_mfma_f32_16x16x32_bf16(a2_0, B2[t][0], acc2[t], 0, 0, 0);
        acc2[t] = __builtin_amdgcn_mfma_f32_16x16x32_bf16(a2_1, B2[t][1], acc2[t], 0, 0, 0);
    }

#pragma unroll
    for (int t = 0; t < 4; ++t) {
#pragma unroll
        for (int r = 0; r < 4; ++r) {
            int row = r0 + q * 4 + r;
            if (row < NN) Zf[(size_t)row * 64 + t * 16 + cl] = acc2[t][r];
        }
    }

    // fused per-column stats over this wave's 16 rows (pad rows masked)
#pragma unroll
    for (int t = 0; t < 4; ++t) {
        float sv = 0.f, qv = 0.f;
#pragma unroll
        for (int r = 0; r < 4; ++r) {
            int row = r0 + q * 4 + r;
            float v = (row < NN) ? acc2[t][r] : 0.f;
            sv += v;
            qv = fmaf(v, v, qv);
        }
        sv += __shfl_xor(sv, 16); sv += __shfl_xor(sv, 32);
        qv += __shfl_xor(qv, 16); qv += __shfl_xor(qv, 32);
        if (lane < 16) {
            sred[0][w][t * 16 + cl] = sv;
            sred[1][w][t * 16 + cl] = qv;
        }
    }
    __syncthreads();
    int tt = threadIdx.x;
    if (tt < 128) {
        int which = tt >> 6, c = tt & 63;
        float tot = sred[which][0][c] + sred[which][1][c] +
                    sred[which][2][c] + sred[which][3][c];
        atomicAdd(&statsL[which * 64 + c], tot);
    }
}

// BN affine (inline from statsL) + ReLU + bf16 pack
__global__ __launch_bounds__(256) void k_bnapply16(const float* __restrict__ Z,
                                                   const float* __restrict__ statsL,
                                                   const float* __restrict__ gammaL,
                                                   const float* __restrict__ betaL,
                                                   unsigned* __restrict__ hb) {
    __shared__ float sa[64];
    __shared__ float sc[64];
    int tt = threadIdx.x;
    if (tt < 64) {
        float mean = statsL[tt] * (1.f / NN);
        float var = statsL[64 + tt] * (1.f / NN) - mean * mean;
        float a = gammaL[tt] * rsqrtf(var + BN_EPS);
        sa[tt] = a;
        sc[tt] = fmaf(-mean, a, betaL[tt]);
    }
    __syncthreads();
    int t = blockIdx.x * 256 + tt;
    if (t >= NN * 8) return;
    int cb = (t & 7) * 8;
    const float4* p = (const float4*)(Z + (size_t)t * 8);
    float4 a = p[0], b = p[1];
    a.x = fmaxf(fmaf(a.x, sa[cb + 0], sc[cb + 0]), 0.f);
    a.y = fmaxf(fmaf(a.y, sa[cb + 1], sc[cb + 1]), 0.f);
    a.z = fmaxf(fmaf(a.z, sa[cb + 2], sc[cb + 2]), 0.f);
    a.w = fmaxf(fmaf(a.w, sa[cb + 3], sc[cb + 3]), 0.f);
    b.x = fmaxf(fmaf(b.x, sa[cb + 4], sc[cb + 4]), 0.f);
    b.y = fmaxf(fmaf(b.y, sa[cb + 5], sc[cb + 5]), 0.f);
    b.z = fmaxf(fmaf(b.z, sa[cb + 6], sc[cb + 6]), 0.f);
    b.w = fmaxf(fmaf(b.w, sa[cb + 7], sc[cb + 7]), 0.f);
    uint4 o;
    o.x = bfpack2(a.x, a.y); o.y = bfpack2(a.z, a.w);
    o.z = bfpack2(b.x, b.y); o.w = bfpack2(b.z, b.w);
    ((uint4*)hb)[t] = o;
}

// final BN apply (affine inline, no relu, f32 out)
__global__ __launch_bounds__(256) void k_apply_aff(const float* __restrict__ B,
                                                   const float* __restrict__ statsL,
                                                   const float* __restrict__ gammaL,
                                                   const float* __restrict__ betaL,
                                                   float* __restrict__ out) {
    __shared__ float sa[64];
    __shared__ float sc[64];
    int t = threadIdx.x;
    if (t < 64) {
        float mean = statsL[t] * (1.f / NN);
        float var = statsL[64 + t] * (1.f / NN) - mean * mean;
        float a = gammaL[t] * rsqrtf(var + BN_EPS);
        sa[t] = a;
        sc[t] = fmaf(-mean, a, betaL[t]);
    }
    __syncthreads();
    int i4 = blockIdx.x * 256 + t;
    if (i4 >= NN * 16) return;
    int cb = (i4 & 15) * 4;
    float4 v = ((const float4*)B)[i4];
    float4 o;
    o.x = fmaf(v.x, sa[cb + 0], sc[cb + 0]);
    o.y = fmaf(v.y, sa[cb + 1], sc[cb + 1]);
    o.z = fmaf(v.z, sa[cb + 2], sc[cb + 2]);
    o.w = fmaf(v.w, sa[cb + 3], sc[cb + 3]);
    ((float4*)out)[i4] = o;
}

extern "C" void kernel_launch(void* const* d_in, const int* in_sizes, int n_in,
                              void* d_out, int out_size, void* d_ws, size_t ws_size,
                              hipStream_t stream) {
    const float* x     = (const float*)d_in[0];
    const int*   ei    = (const int*)d_in[1];   // [2][E]
    const float* W1    = (const float*)d_in[2];
    const float* b1    = (const float*)d_in[3];
    const float* W2    = (const float*)d_in[4];
    const float* b2    = (const float*)d_in[5];
    const float* gamma = (const float*)d_in[6];
    const float* beta  = (const float*)d_in[7];
    float* out = (float*)d_out;

    const int* src = ei;        // edge_index[0]
    const int* dst = ei + EE;   // edge_index[1]

    char* w = (char*)d_ws;
    unsigned*       Zb  = (unsigned*)w;       w += (size_t)NPAD * DD * 2;       // bf16 agg out (padded)
    float*          Zf  = (float*)w;          w += (size_t)NN * DD * 4;         // f32 mlp out
    unsigned*       Hb  = (unsigned*)w;       w += (size_t)NN * DD * 2;         // bf16 bn out
    unsigned*       Xb  = (unsigned*)w;       w += (size_t)NN * DD * 2;         // bf16 x
    int*            col = (int*)w;            w += (size_t)NN * CAP * 4;        // padded CSR
    unsigned long long* bucket = (unsigned long long*)w;
    w += (size_t)NPART * BCAP * 8;
    int*            cursor    = (int*)w;      w += (size_t)NN * 4;              // degree after scatter
    int*            bucketCnt = (int*)w;      w += 128 * 4;
    float*          stats     = (float*)w;    w += 384 * 4;                     // 3 layers x 128
    unsigned short* Wb        = (unsigned short*)w; w += 3 * 2 * 4096 * 2;      // bf16 W^T

    // ---- setup + CSR build ----
    k_setup<<<NB_SETUP, 256, 0, stream>>>(x, Xb, W1, W2, Wb, bucketCnt, stats);
    k_build<<<NB_BUCKET, 1024, 0, stream>>>(src, dst, bucket, bucketCnt, cursor);
    k_scatter<<<NPART * NSCAT, 256, 0, stream>>>(bucket, bucketCnt, cursor, col);

    // ---- layer 0 ----
    k_agg4<<<NB_AGG, 256, 0, stream>>>(Xb, cursor, col, Zb);
    k_mlp_mfma<<<NB_MLP, 256, 0, stream>>>((unsigned short*)Zb, Wb, b1, b2, Zf, stats);
    k_bnapply16<<<NB_ELT8, 256, 0, stream>>>(Zf, stats, gamma, beta, Hb);

    // ---- layer 1 ----
    k_agg4<<<NB_AGG, 256, 0, stream>>>(Hb, cursor, col, Zb);
    k_mlp_mfma<<<NB_MLP, 256, 0, stream>>>((unsigned short*)Zb, Wb + 8192, b1 + 64, b2 + 64, Zf, stats + 128);
    k_bnapply16<<<NB_ELT8, 256, 0, stream>>>(Zf, stats + 128, gamma + 64, beta + 64, Hb);

    // ---- layer 2 ----
    k_agg4<<<NB_AGG, 256, 0, stream>>>(Hb, cursor, col, Zb);
    k_mlp_mfma<<<NB_MLP, 256, 0, stream>>>((unsigned short*)Zb, Wb + 16384, b1 + 128, b2 + 128, Zf, stats + 256);
    k_apply_aff<<<NB_APPLY, 256, 0, stream>>>(Zf, stats + 256, gamma + 128, beta + 128, out);
}

// Round 14
// 234.921 us; speedup vs baseline: 1.2497x; 1.0196x over previous
//
#include <hip/hip_runtime.h>

#define NN 50000
#define NPAD 50064             // padded rows for MFMA tail reads
#define EE 800000
#define DD 64
#define BN_EPS 1e-5f

#define NPART 8
#define PART_NODES 6250        // 50000/8
#define CAP 64                 // padded CSR slots per node
#define BCAP 131072            // bucket capacity per partition
#define NSCAT 32               // scatter blocks per partition
#define NB_BUCKET 782          // ceil(800000/1024)
#define NB_AGG  12500          // 4 nodes (waves) per block, grid exact
#define NB_MLP  782            // 64 rows per block (4 waves x 16)
#define NB_SETUP 1563          // covers 400000 cvt threads
#define NB_APPLY 3125

typedef __attribute__((ext_vector_type(8))) short short8v;   // 8 bf16 = 4 VGPR
typedef __attribute__((ext_vector_type(4))) float float4v;   // MFMA acc

__device__ __forceinline__ unsigned bfpack2(float a, float b) {
    union { float f; unsigned u; } ua, ub;
    ua.f = a; ub.f = b;
    unsigned ra = ua.u + 0x7fffu + ((ua.u >> 16) & 1u);
    unsigned rb = ub.u + 0x7fffu + ((ub.u >> 16) & 1u);
    return (ra >> 16) | (rb & 0xffff0000u);
}

__device__ __forceinline__ unsigned short bf16of(float v) {
    union { float f; unsigned u; } x; x.f = v;
    unsigned r = x.u + 0x7fffu + ((x.u >> 16) & 1u);
    return (unsigned short)(r >> 16);
}

// setup: x -> bf16, W -> bf16 transposed, zero bucketCnt + stats
__global__ __launch_bounds__(256) void k_setup(const float* __restrict__ x,
                                               unsigned* __restrict__ xb,
                                               const float* __restrict__ W1,
                                               const float* __restrict__ W2,
                                               unsigned short* __restrict__ Wb,
                                               int* __restrict__ bucketCnt,
                                               float* __restrict__ stats) {
    int t = blockIdx.x * 256 + threadIdx.x;
    if (t < NN * 8) {
        const float4* p = (const float4*)(x + (size_t)t * 8);
        float4 a = p[0], b = p[1];
        uint4 o;
        o.x = bfpack2(a.x, a.y); o.y = bfpack2(a.z, a.w);
        o.z = bfpack2(b.x, b.y); o.w = bfpack2(b.z, b.w);
        ((uint4*)xb)[t] = o;
    }
    if (t < 3 * 2 * 4096) {
        int l = t / 8192;
        int rem = t - l * 8192;
        int m = rem / 4096;
        int e = rem - m * 4096;
        int c = e >> 6, k = e & 63;
        const float* W = (m == 0 ? W1 : W2) + l * 4096;
        Wb[t] = bf16of(W[k * 64 + c]);
    }
    if (t < 128) bucketCnt[t] = 0;
    else if (t < 512) stats[t - 128] = 0.f;
}

// phase A: bucket edges by dst partition (one pass over edges) + zero cursor
__global__ __launch_bounds__(1024) void k_build(const int* __restrict__ src,
                                                const int* __restrict__ dst,
                                                unsigned long long* __restrict__ bucket,
                                                int* __restrict__ bucketCnt,
                                                int* __restrict__ cursor) {
    __shared__ int lcnt[8];
    __shared__ int lbase[8];
    int t = threadIdx.x;
    int g = blockIdx.x * 1024 + t;
    if (g < NN) cursor[g] = 0;
    if (t < 8) lcnt[t] = 0;
    __syncthreads();
    int d = 0, s = 0, p = 0, loc = 0;
    bool ok = (g < EE);
    if (ok) {
        d = __builtin_nontemporal_load(dst + g);
        s = __builtin_nontemporal_load(src + g);
        p = (unsigned)d / PART_NODES;
        loc = atomicAdd(&lcnt[p], 1);
    }
    __syncthreads();
    if (t < 8) lbase[t] = atomicAdd(&bucketCnt[t * 16], lcnt[t]);
    __syncthreads();
    if (ok) {
        unsigned long long v = ((unsigned long long)(unsigned)s << 32) | (unsigned)d;
        bucket[(size_t)p * BCAP + lbase[p] + loc] = v;
    }
}

// phase B: scatter bucket p into col slice p (dirty lines stay on one XCD)
__global__ __launch_bounds__(256) void k_scatter(const unsigned long long* __restrict__ bucket,
                                                 const int* __restrict__ bucketCnt,
                                                 int* __restrict__ cursor,
                                                 int* __restrict__ col) {
    int p = blockIdx.x & 7;
    int cnt = bucketCnt[p * 16];
    const unsigned long long* b = bucket + (size_t)p * BCAP;
    for (int i = (blockIdx.x >> 3) * 256 + threadIdx.x; i < cnt; i += NSCAT * 256) {
        unsigned long long v = __builtin_nontemporal_load(b + i);
        int d = (int)(v & 0xffffffffu);
        int s = (int)(v >> 32);
        int pos = atomicAdd(&cursor[d], 1);
        col[d * CAP + pos] = s;
    }
}

// z[i,:] = self + sum_j val(h[j,:]); val = relu(a*x+c) per element when FUSE
// (BN+ReLU of previous layer, applied per gathered row — VALU is idle in this
// latency-bound gather, so the redundant per-neighbor affine is free).
// Wave per node: lane = slot*8 + li; 8 slots x unroll-2 = 16 rows in flight.
template<int FUSE>
__global__ __launch_bounds__(256) void k_agg4(const unsigned* __restrict__ hb,
                                              const int* __restrict__ deg,
                                              const int* __restrict__ col,
                                              const float* __restrict__ statsL,
                                              const float* __restrict__ gammaL,
                                              const float* __restrict__ betaL,
                                              unsigned* __restrict__ outZb) {
    __shared__ float sa[64];
    __shared__ float sc[64];
    if (FUSE) {
        int tt = threadIdx.x;
        if (tt < 64) {
            float mean = statsL[tt] * (1.f / NN);
            float var = statsL[64 + tt] * (1.f / NN) - mean * mean;
            float a = gammaL[tt] * rsqrtf(var + BN_EPS);
            sa[tt] = a;
            sc[tt] = fmaf(-mean, a, betaL[tt]);
        }
        __syncthreads();
    }
    int node = blockIdx.x * 4 + (threadIdx.x >> 6);   // grid exact: 12500*4
    int lane = threadIdx.x & 63;
    int li = lane & 7;
    int slot = lane >> 3;
    int dn = deg[node];
    int base = node * CAP;
    const uint4* hb4 = (const uint4*)hb;
    float a8[8], c8[8];
    if (FUSE) {
#pragma unroll
        for (int j = 0; j < 8; ++j) { a8[j] = sa[li * 8 + j]; c8[j] = sc[li * 8 + j]; }
    }
    float acc[8];
#pragma unroll
    for (int i = 0; i < 8; ++i) acc[i] = 0.f;

#define UNPK_ADD(U)                                                      \
    {                                                                    \
        uint4 _u = (U);                                                  \
        union { unsigned u; float f; } l0, h0, l1, h1, l2, h2, l3, h3;   \
        l0.u = _u.x << 16; h0.u = _u.x & 0xffff0000u;                    \
        l1.u = _u.y << 16; h1.u = _u.y & 0xffff0000u;                    \
        l2.u = _u.z << 16; h2.u = _u.z & 0xffff0000u;                    \
        l3.u = _u.w << 16; h3.u = _u.w & 0xffff0000u;                    \
        float v[8] = {l0.f, h0.f, l1.f, h1.f, l2.f, h2.f, l3.f, h3.f};   \
        _Pragma("unroll")                                                \
        for (int j = 0; j < 8; ++j)                                      \
            acc[j] += FUSE ? fmaxf(fmaf(v[j], a8[j], c8[j]), 0.f) : v[j];\
    }

    if (slot == 0)
        UNPK_ADD(hb4[(size_t)node * 8 + li]);   // self row

    int k = slot;
    for (; k + 8 < dn; k += 16) {
        int s0 = __builtin_nontemporal_load(col + base + k);
        int s1 = __builtin_nontemporal_load(col + base + k + 8);
        uint4 u0 = hb4[(size_t)s0 * 8 + li];
        uint4 u1 = hb4[(size_t)s1 * 8 + li];
        UNPK_ADD(u0);
        UNPK_ADD(u1);
    }
    if (k < dn) {
        int s0 = __builtin_nontemporal_load(col + base + k);
        UNPK_ADD(hb4[(size_t)s0 * 8 + li]);
    }
#undef UNPK_ADD

#pragma unroll
    for (int i = 0; i < 8; ++i) acc[i] += __shfl_xor(acc[i], 8);
#pragma unroll
    for (int i = 0; i < 8; ++i) acc[i] += __shfl_xor(acc[i], 16);
#pragma unroll
    for (int i = 0; i < 8; ++i) acc[i] += __shfl_xor(acc[i], 32);

    if (slot == 0) {
        uint4 o;
        o.x = bfpack2(acc[0], acc[1]);
        o.y = bfpack2(acc[2], acc[3]);
        o.z = bfpack2(acc[4], acc[5]);
        o.w = bfpack2(acc[6], acc[7]);
        ((uint4*)outZb)[(size_t)node * 8 + li] = o;
    }
}

// MFMA MLP + fused BN stats. OUTF32=0: write bf16 Mb (via LDS repack, 16B
// stores) for the next layer's fused-BN gather. OUTF32=1: write f32 Zf (final
// layer, full precision for the output BN). Stats always from f32 acc2.
template<int OUTF32>
__global__ __launch_bounds__(256) void k_mlp_mfma(const unsigned short* __restrict__ Zb,
                                                  const unsigned short* __restrict__ WbL,
                                                  const float* __restrict__ b1,
                                                  const float* __restrict__ b2,
                                                  unsigned short* __restrict__ Mb,
                                                  float* __restrict__ Zf,
                                                  float* __restrict__ statsL) {
    __shared__ unsigned short sm[4][16 * 72];   // padded stride 72 u16
    __shared__ float sred[2][4][64];
    int w = threadIdx.x >> 6;
    int lane = threadIdx.x & 63;
    int q = lane >> 4;
    int cl = lane & 15;
    int r0 = blockIdx.x * 64 + w * 16;

    short8v B1[4][2], B2[4][2];
#pragma unroll
    for (int t = 0; t < 4; ++t) {
#pragma unroll
        for (int h = 0; h < 2; ++h) {
            B1[t][h] = *(const short8v*)(WbL + ((t * 16 + cl) * 64 + h * 32 + q * 8));
            B2[t][h] = *(const short8v*)(WbL + 4096 + ((t * 16 + cl) * 64 + h * 32 + q * 8));
        }
    }

    const unsigned short* zr = Zb + (size_t)(r0 + cl) * 64;
    short8v a0 = *(const short8v*)(zr + q * 8);
    short8v a1 = *(const short8v*)(zr + 32 + q * 8);

    float4v acc1[4];
#pragma unroll
    for (int t = 0; t < 4; ++t) {
        float b = b1[t * 16 + cl];
        acc1[t] = (float4v){b, b, b, b};
        acc1[t] = __builtin_amdgcn_mfma_f32_16x16x32_bf16(a0, B1[t][0], acc1[t], 0, 0, 0);
        acc1[t] = __builtin_amdgcn_mfma_f32_16x16x32_bf16(a1, B1[t][1], acc1[t], 0, 0, 0);
    }

    unsigned short* s = sm[w];
#pragma unroll
    for (int t = 0; t < 4; ++t) {
#pragma unroll
        for (int r = 0; r < 4; ++r) {
            float v = fmaxf(acc1[t][r], 0.f);
            s[(q * 4 + r) * 72 + t * 16 + cl] = bf16of(v);
        }
    }

    short8v a2_0 = *(const short8v*)(s + cl * 72 + q * 8);
    short8v a2_1 = *(const short8v*)(s + cl * 72 + 32 + q * 8);

    float4v acc2[4];
#pragma unroll
    for (int t = 0; t < 4; ++t) {
        float b = b2[t * 16 + cl];
        acc2[t] = (float4v){b, b, b, b};
        acc2[t] = __builtin_amdgcn_mfma_f32_16x16x32_bf16(a2_0, B2[t][0], acc2[t], 0, 0, 0);
        acc2[t] = __builtin_amdgcn_mfma_f32_16x16x32_bf16(a2_1, B2[t][1], acc2[t], 0, 0, 0);
    }

    if (OUTF32) {
#pragma unroll
        for (int t = 0; t < 4; ++t) {
#pragma unroll
            for (int r = 0; r < 4; ++r) {
                int row = r0 + q * 4 + r;
                if (row < NN) Zf[(size_t)row * 64 + t * 16 + cl] = acc2[t][r];
            }
        }
    } else {
        // bf16 repack through the (now free) LDS tile -> 16B coalesced stores
#pragma unroll
        for (int t = 0; t < 4; ++t) {
#pragma unroll
            for (int r = 0; r < 4; ++r) {
                s[(q * 4 + r) * 72 + t * 16 + cl] = bf16of(acc2[t][r]);
            }
        }
        short8v m0 = *(const short8v*)(s + cl * 72 + q * 8);
        short8v m1 = *(const short8v*)(s + cl * 72 + 32 + q * 8);
        int orow = r0 + cl;
        if (orow < NN) {
            *(short8v*)(Mb + (size_t)orow * 64 + q * 8) = m0;
            *(short8v*)(Mb + (size_t)orow * 64 + 32 + q * 8) = m1;
        }
    }

    // fused per-column stats over this wave's 16 rows (pad rows masked)
#pragma unroll
    for (int t = 0; t < 4; ++t) {
        float sv = 0.f, qv = 0.f;
#pragma unroll
        for (int r = 0; r < 4; ++r) {
            int row = r0 + q * 4 + r;
            float v = (row < NN) ? acc2[t][r] : 0.f;
            sv += v;
            qv = fmaf(v, v, qv);
        }
        sv += __shfl_xor(sv, 16); sv += __shfl_xor(sv, 32);
        qv += __shfl_xor(qv, 16); qv += __shfl_xor(qv, 32);
        if (lane < 16) {
            sred[0][w][t * 16 + cl] = sv;
            sred[1][w][t * 16 + cl] = qv;
        }
    }
    __syncthreads();
    int tt = threadIdx.x;
    if (tt < 128) {
        int which = tt >> 6, c = tt & 63;
        float tot = sred[which][0][c] + sred[which][1][c] +
                    sred[which][2][c] + sred[which][3][c];
        atomicAdd(&statsL[which * 64 + c], tot);
    }
}

// final BN apply (affine inline, no relu, f32 out)
__global__ __launch_bounds__(256) void k_apply_aff(const float* __restrict__ B,
                                                   const float* __restrict__ statsL,
                                                   const float* __restrict__ gammaL,
                                                   const float* __restrict__ betaL,
                                                   float* __restrict__ out) {
    __shared__ float sa[64];
    __shared__ float sc[64];
    int t = threadIdx.x;
    if (t < 64) {
        float mean = statsL[t] * (1.f / NN);
        float var = statsL[64 + t] * (1.f / NN) - mean * mean;
        float a = gammaL[t] * rsqrtf(var + BN_EPS);
        sa[t] = a;
        sc[t] = fmaf(-mean, a, betaL[t]);
    }
    __syncthreads();
    int i4 = blockIdx.x * 256 + t;
    if (i4 >= NN * 16) return;
    int cb = (i4 & 15) * 4;
    float4 v = ((const float4*)B)[i4];
    float4 o;
    o.x = fmaf(v.x, sa[cb + 0], sc[cb + 0]);
    o.y = fmaf(v.y, sa[cb + 1], sc[cb + 1]);
    o.z = fmaf(v.z, sa[cb + 2], sc[cb + 2]);
    o.w = fmaf(v.w, sa[cb + 3], sc[cb + 3]);
    ((float4*)out)[i4] = o;
}

extern "C" void kernel_launch(void* const* d_in, const int* in_sizes, int n_in,
                              void* d_out, int out_size, void* d_ws, size_t ws_size,
                              hipStream_t stream) {
    const float* x     = (const float*)d_in[0];
    const int*   ei    = (const int*)d_in[1];   // [2][E]
    const float* W1    = (const float*)d_in[2];
    const float* b1    = (const float*)d_in[3];
    const float* W2    = (const float*)d_in[4];
    const float* b2    = (const float*)d_in[5];
    const float* gamma = (const float*)d_in[6];
    const float* beta  = (const float*)d_in[7];
    float* out = (float*)d_out;

    const int* src = ei;        // edge_index[0]
    const int* dst = ei + EE;   // edge_index[1]

    char* w = (char*)d_ws;
    unsigned*       Ab  = (unsigned*)w;       w += (size_t)NPAD * DD * 2;       // bf16 agg out (padded)
    unsigned*       Mb  = (unsigned*)w;       w += (size_t)NPAD * DD * 2;       // bf16 mlp out (padded)
    unsigned*       Xb  = (unsigned*)w;       w += (size_t)NPAD * DD * 2;       // bf16 x
    float*          Zf  = (float*)w;          w += (size_t)NN * DD * 4;         // f32 mlp out (layer 2)
    int*            col = (int*)w;            w += (size_t)NN * CAP * 4;        // padded CSR
    unsigned long long* bucket = (unsigned long long*)w;
    w += (size_t)NPART * BCAP * 8;
    int*            cursor    = (int*)w;      w += (size_t)NN * 4;              // degree after scatter
    int*            bucketCnt = (int*)w;      w += 128 * 4;
    float*          stats     = (float*)w;    w += 384 * 4;                     // 3 layers x 128
    unsigned short* Wb        = (unsigned short*)w; w += 3 * 2 * 4096 * 2;      // bf16 W^T

    // ---- setup + CSR build ----
    k_setup<<<NB_SETUP, 256, 0, stream>>>(x, Xb, W1, W2, Wb, bucketCnt, stats);
    k_build<<<NB_BUCKET, 1024, 0, stream>>>(src, dst, bucket, bucketCnt, cursor);
    k_scatter<<<NPART * NSCAT, 256, 0, stream>>>(bucket, bucketCnt, cursor, col);

    // ---- layer 0 ----
    k_agg4<0><<<NB_AGG, 256, 0, stream>>>(Xb, cursor, col, nullptr, nullptr, nullptr, Ab);
    k_mlp_mfma<0><<<NB_MLP, 256, 0, stream>>>((unsigned short*)Ab, Wb, b1, b2,
                                              (unsigned short*)Mb, nullptr, stats);

    // ---- layer 1 (BN0+ReLU fused into the gather) ----
    k_agg4<1><<<NB_AGG, 256, 0, stream>>>(Mb, cursor, col, stats, gamma, beta, Ab);
    k_mlp_mfma<0><<<NB_MLP, 256, 0, stream>>>((unsigned short*)Ab, Wb + 8192, b1 + 64, b2 + 64,
                                              (unsigned short*)Mb, nullptr, stats + 128);

    // ---- layer 2 (BN1+ReLU fused into the gather; f32 out for final BN) ----
    k_agg4<1><<<NB_AGG, 256, 0, stream>>>(Mb, cursor, col, stats + 128, gamma + 64, beta + 64, Ab);
    k_mlp_mfma<1><<<NB_MLP, 256, 0, stream>>>((unsigned short*)Ab, Wb + 16384, b1 + 128, b2 + 128,
                                              nullptr, Zf, stats + 256);
    k_apply_aff<<<NB_APPLY, 256, 0, stream>>>(Zf, stats + 256, gamma + 128, beta + 128, out);
}